// Round 1
// baseline (304.820 us; speedup 1.0000x reference)
//
#include <hip/hip_runtime.h>
#include <math.h>

constexpr int B_  = 128;
constexpr int A_  = 2048;
constexpr int C_  = 128;
constexpr int H_  = 512;
constexpr int S_  = 3;
constexpr int NR_ = 2;
constexpr int PR_ = C_ + 3 + S_;      // 134
constexpr int PW_ = 3 * C_ + 3 + S_;  // 390

__device__ __forceinline__ float sigmoidf_(float x) { return 1.0f / (1.0f + expf(-x)); }
__device__ __forceinline__ float softplusf_(float x) {
  return fmaxf(x, 0.0f) + log1pf(expf(-fabsf(x)));
}

__device__ __forceinline__ float waveReduceSum(float v) {
#pragma unroll
  for (int off = 32; off; off >>= 1) v += __shfl_xor(v, off, 64);
  return v;
}
__device__ __forceinline__ float waveReduceMax(float v) {
#pragma unroll
  for (int off = 32; off; off >>= 1) v = fmaxf(v, __shfl_xor(v, off, 64));
  return v;
}

// blockDim == 256 (4 waves)
__device__ __forceinline__ float blockReduceSum(float v, float* rbuf) {
  int tid = threadIdx.x;
  v = waveReduceSum(v);
  if ((tid & 63) == 0) rbuf[tid >> 6] = v;
  __syncthreads();
  float r = rbuf[0] + rbuf[1] + rbuf[2] + rbuf[3];
  __syncthreads();
  return r;
}
__device__ __forceinline__ float blockReduceMax(float v, float* rbuf) {
  int tid = threadIdx.x;
  v = waveReduceMax(v);
  if ((tid & 63) == 0) rbuf[tid >> 6] = v;
  __syncthreads();
  float r = fmaxf(fmaxf(rbuf[0], rbuf[1]), fmaxf(rbuf[2], rbuf[3]));
  __syncthreads();
  return r;
}

// ---------------------------------------------------------------------------
// Kernel 1: projections. One wave per output scalar (K=512 dot).
// pr[r][b][p] = h[b,:].W_read[r,p,:] + b_read[r,p]
// pw[b][p]    = h[b,:].W_write[p,:]  + b_write[p]
// ---------------------------------------------------------------------------
__global__ __launch_bounds__(256) void proj_kernel(
    const float* __restrict__ h, const float* __restrict__ Wr,
    const float* __restrict__ br, const float* __restrict__ Ww,
    const float* __restrict__ bw, float* __restrict__ pr, float* __restrict__ pw) {
  constexpr int NPR = NR_ * B_ * PR_;   // 34304
  constexpr int NPW = B_ * PW_;         // 49920
  int wave = (blockIdx.x * blockDim.x + threadIdx.x) >> 6;
  int lane = threadIdx.x & 63;
  const float* wrow;
  const float* hrow;
  float bias;
  float* outp;
  if (wave < NPR) {
    int r = wave / (B_ * PR_);
    int rem = wave - r * (B_ * PR_);
    int b = rem / PR_;
    int p = rem - b * PR_;
    wrow = Wr + (size_t)(r * PR_ + p) * H_;
    hrow = h + (size_t)b * H_;
    bias = br[r * PR_ + p];
    outp = pr + wave;
  } else {
    int w2 = wave - NPR;
    if (w2 >= NPW) return;
    int b = w2 / PW_;
    int p = w2 - b * PW_;
    wrow = Ww + (size_t)p * H_;
    hrow = h + (size_t)b * H_;
    bias = bw[p];
    outp = pw + w2;
  }
  const float4* w4 = (const float4*)wrow;
  const float4* h4 = (const float4*)hrow;
  float4 a0 = h4[(lane << 1)];
  float4 a1 = h4[(lane << 1) + 1];
  float4 b0 = w4[(lane << 1)];
  float4 b1 = w4[(lane << 1) + 1];
  float acc = a0.x * b0.x;
  acc = fmaf(a0.y, b0.y, acc);
  acc = fmaf(a0.z, b0.z, acc);
  acc = fmaf(a0.w, b0.w, acc);
  acc = fmaf(a1.x, b1.x, acc);
  acc = fmaf(a1.y, b1.y, acc);
  acc = fmaf(a1.z, b1.z, acc);
  acc = fmaf(a1.w, b1.w, acc);
  acc = waveReduceSum(acc);
  if (lane == 0) *outp = acc + bias;
}

// ---------------------------------------------------------------------------
// Kernel 2: per (head,b): q = sigmoid(query), qn = max(||q||, eps), scalar
// params (beta, gate, shift-softmax, gamma). grid = 3*B, block = 64.
// ---------------------------------------------------------------------------
__global__ __launch_bounds__(64) void headprep_kernel(
    const float* __restrict__ pr, const float* __restrict__ pw,
    float* __restrict__ qbuf, float* __restrict__ qn, float* __restrict__ pars) {
  int hb = blockIdx.x;          // hd*B + b
  int hd = hb >> 7;
  int b = hb & (B_ - 1);
  int lane = threadIdx.x;
  const float* src = (hd < 2) ? (pr + (size_t)hb * PR_) : (pw + (size_t)b * PW_);
  float2 raw = ((const float2*)src)[lane];   // c = lane*2, lane*2+1
  float q0 = sigmoidf_(raw.x);
  float q1 = sigmoidf_(raw.y);
  ((float2*)(qbuf + (size_t)hb * C_))[lane] = make_float2(q0, q1);
  float ss = q0 * q0 + q1 * q1;
  ss = waveReduceSum(ss);
  if (lane == 0) {
    qn[hb] = fmaxf(sqrtf(ss), 1e-8f);
    float braw = src[C_];
    float graw = src[C_ + 1];
    float s0 = src[C_ + 2], s1 = src[C_ + 3], s2 = src[C_ + 4];
    float gmraw = src[C_ + 5];
    float mx = fmaxf(s0, fmaxf(s1, s2));
    float e0 = expf(s0 - mx), e1 = expf(s1 - mx), e2 = expf(s2 - mx);
    float inv = 1.0f / (e0 + e1 + e2);
    float* pp = pars + hb * 8;
    pp[0] = softplusf_(braw) + 1.0f;   // beta
    pp[1] = sigmoidf_(graw);           // gate
    pp[2] = e0 * inv;                  // shift_w[0]
    pp[3] = e1 * inv;
    pp[4] = e2 * inv;
    pp[5] = softplusf_(gmraw) + 1.0f;  // gamma
  }
}

// ---------------------------------------------------------------------------
// Kernel 3: pass over mem. Half-wave (32 lanes) per row: 3 dots + sum(m^2).
// Block: 256 threads handles (b, 64 rows). grid = B * A/64 = 4096.
// sim[hd][b][a] = dot(q, m) / (qn * max(||m||,eps))
// ---------------------------------------------------------------------------
__global__ __launch_bounds__(256) void sim_kernel(
    const float* __restrict__ mem, const float* __restrict__ qbuf,
    const float* __restrict__ qn, float* __restrict__ sim) {
  __shared__ __align__(16) float qs[3 * C_];
  __shared__ float qnl[3];
  int b = blockIdx.x >> 5;
  int chunk = blockIdx.x & 31;
  int rowbase = chunk << 6;
  int tid = threadIdx.x;
  for (int idx = tid; idx < 3 * C_; idx += 256) {
    int hd = idx >> 7;
    int c = idx & (C_ - 1);
    qs[idx] = qbuf[(size_t)(hd * B_ + b) * C_ + c];
  }
  if (tid < 3) qnl[tid] = qn[tid * B_ + b];
  __syncthreads();

  int wv = tid >> 6;
  int lane = tid & 63;
  int half = lane >> 5;
  int l32 = lane & 31;
  const float4* q40 = (const float4*)(qs);
  const float4* q41 = (const float4*)(qs + C_);
  const float4* q42 = (const float4*)(qs + 2 * C_);
  float4 qv0 = q40[l32];
  float4 qv1 = q41[l32];
  float4 qv2 = q42[l32];
  float iqn0 = 1.0f / qnl[0], iqn1 = 1.0f / qnl[1], iqn2 = 1.0f / qnl[2];

#pragma unroll
  for (int i = 0; i < 8; i++) {
    int pairIdx = (wv << 3) + i;
    int row = rowbase + (pairIdx << 1) + half;
    const float4* mrow = (const float4*)(mem + ((size_t)b * A_ + row) * C_);
    float4 m = mrow[l32];
    float d0 = m.x * qv0.x;
    d0 = fmaf(m.y, qv0.y, d0); d0 = fmaf(m.z, qv0.z, d0); d0 = fmaf(m.w, qv0.w, d0);
    float d1 = m.x * qv1.x;
    d1 = fmaf(m.y, qv1.y, d1); d1 = fmaf(m.z, qv1.z, d1); d1 = fmaf(m.w, qv1.w, d1);
    float d2 = m.x * qv2.x;
    d2 = fmaf(m.y, qv2.y, d2); d2 = fmaf(m.z, qv2.z, d2); d2 = fmaf(m.w, qv2.w, d2);
    float ss = m.x * m.x;
    ss = fmaf(m.y, m.y, ss); ss = fmaf(m.z, m.z, ss); ss = fmaf(m.w, m.w, ss);
#pragma unroll
    for (int off = 16; off; off >>= 1) {
      d0 += __shfl_xor(d0, off, 64);
      d1 += __shfl_xor(d1, off, 64);
      d2 += __shfl_xor(d2, off, 64);
      ss += __shfl_xor(ss, off, 64);
    }
    if (l32 == 0) {
      float imn = 1.0f / fmaxf(sqrtf(ss), 1e-8f);
      sim[(size_t)(0 * B_ + b) * A_ + row] = d0 * iqn0 * imn;
      sim[(size_t)(1 * B_ + b) * A_ + row] = d1 * iqn1 * imn;
      sim[(size_t)(2 * B_ + b) * A_ + row] = d2 * iqn2 * imn;
    }
  }
}

// ---------------------------------------------------------------------------
// Kernel 4: zero the read_vectors region of d_out (atomically accumulated).
// ---------------------------------------------------------------------------
__global__ void zero_rv_kernel(float* __restrict__ rv) {
  int idx = blockIdx.x * blockDim.x + threadIdx.x;
  if (idx < NR_ * B_ * C_) rv[idx] = 0.0f;
}

// ---------------------------------------------------------------------------
// Kernel 5: attention per (head,b). softmax(beta*sim) -> gate mix -> circular
// shift conv -> gamma sharpen -> normalize. Writes IN-PLACE over sim.
// grid = 3*B = 384, block = 256 (each thread owns 8 strided elements).
// ---------------------------------------------------------------------------
__global__ __launch_bounds__(256) void attn_kernel(
    const float* __restrict__ sim, const float* __restrict__ ra,
    const float* __restrict__ wa, const float* __restrict__ pars,
    float* __restrict__ attn) {
  __shared__ float wg[A_];
  __shared__ float rbuf[4];
  int hb = blockIdx.x;
  int hd = hb >> 7;
  int b = hb & (B_ - 1);
  int tid = threadIdx.x;
  const float* pp = pars + hb * 8;
  float beta = pp[0], gate = pp[1], sw0 = pp[2], sw1 = pp[3], sw2 = pp[4], gamma = pp[5];
  const float* simrow = sim + (size_t)hb * A_;
  const float* prev = (hd < 2) ? (ra + (size_t)hb * A_) : (wa + (size_t)b * A_);
  float* outrow = attn + (size_t)hb * A_;

  float s[8];
  float mx = -1e30f;
#pragma unroll
  for (int i = 0; i < 8; i++) {
    s[i] = simrow[tid + (i << 8)];
    mx = fmaxf(mx, s[i]);
  }
  mx = blockReduceMax(mx, rbuf);
  float p[8];
  float lsum = 0.0f;
#pragma unroll
  for (int i = 0; i < 8; i++) {
    p[i] = expf(beta * (s[i] - mx));
    lsum += p[i];
  }
  float tot = blockReduceSum(lsum, rbuf);
  float inv = 1.0f / tot;
#pragma unroll
  for (int i = 0; i < 8; i++) {
    int a = tid + (i << 8);
    wg[a] = fmaf(gate, p[i] * inv, (1.0f - gate) * prev[a]);
  }
  __syncthreads();
  float lsum2 = 0.0f;
#pragma unroll
  for (int i = 0; i < 8; i++) {
    int a = tid + (i << 8);
    float ws = sw0 * wg[(a + 1) & (A_ - 1)] + sw1 * wg[a] + sw2 * wg[(a - 1) & (A_ - 1)];
    float wp = (ws > 0.0f) ? exp2f(gamma * log2f(ws)) : 0.0f;
    p[i] = wp;
    lsum2 += wp;
  }
  float tot2 = blockReduceSum(lsum2, rbuf);
  float inv2 = 1.0f / (tot2 + 1e-12f);
#pragma unroll
  for (int i = 0; i < 8; i++) {
    outrow[tid + (i << 8)] = p[i] * inv2;
  }
}

// ---------------------------------------------------------------------------
// Kernel 6: second pass over mem: read_vectors (atomic after LDS reduce) and
// new_mem = mem*(1 - w*e) + w*a. Block: (b, 256-row chunk). grid = 1024.
// Threads: rowlane = tid&31 -> c-quad; rowoff = tid>>5 -> row parity (8).
// ---------------------------------------------------------------------------
__global__ __launch_bounds__(256) void update_kernel(
    const float* __restrict__ mem, const float* __restrict__ attn,
    const float* __restrict__ pw, float* __restrict__ rv,
    float* __restrict__ nmem) {
  __shared__ float att0[256], att1[256], attw[256];
  __shared__ float4 red0[256];
  __shared__ float4 red1[256];
  int b = blockIdx.x >> 3;
  int chunk = blockIdx.x & 7;
  int rowbase = chunk << 8;
  int tid = threadIdx.x;
  att0[tid] = attn[(size_t)(0 * B_ + b) * A_ + rowbase + tid];
  att1[tid] = attn[(size_t)(1 * B_ + b) * A_ + rowbase + tid];
  attw[tid] = attn[(size_t)(2 * B_ + b) * A_ + rowbase + tid];
  __syncthreads();

  int rowlane = tid & 31;
  int rowoff = tid >> 5;
  int c0 = rowlane << 2;
  const float* pwrow = pw + (size_t)b * PW_;
  float2 eA = *(const float2*)(pwrow + C_ + 6 + c0);        // erase at offset 134
  float2 eB = *(const float2*)(pwrow + C_ + 6 + c0 + 2);
  float2 aA = *(const float2*)(pwrow + 2 * C_ + 6 + c0);    // add at offset 262
  float2 aB = *(const float2*)(pwrow + 2 * C_ + 6 + c0 + 2);
  float e0 = sigmoidf_(eA.x), e1 = sigmoidf_(eA.y), e2 = sigmoidf_(eB.x), e3 = sigmoidf_(eB.y);
  float ad0 = sigmoidf_(aA.x), ad1 = sigmoidf_(aA.y), ad2 = sigmoidf_(aB.x), ad3 = sigmoidf_(aB.y);

  float4 acc0 = make_float4(0.f, 0.f, 0.f, 0.f);
  float4 acc1 = make_float4(0.f, 0.f, 0.f, 0.f);

#pragma unroll 4
  for (int i = 0; i < 32; i++) {
    int ridx = (i << 3) + rowoff;
    int row = rowbase + ridx;
    size_t base = ((size_t)b * A_ + row) * C_ + c0;
    float4 m = *(const float4*)(mem + base);
    float w0 = att0[ridx];
    float w1 = att1[ridx];
    float ww = attw[ridx];
    acc0.x = fmaf(w0, m.x, acc0.x);
    acc0.y = fmaf(w0, m.y, acc0.y);
    acc0.z = fmaf(w0, m.z, acc0.z);
    acc0.w = fmaf(w0, m.w, acc0.w);
    acc1.x = fmaf(w1, m.x, acc1.x);
    acc1.y = fmaf(w1, m.y, acc1.y);
    acc1.z = fmaf(w1, m.z, acc1.z);
    acc1.w = fmaf(w1, m.w, acc1.w);
    float4 nm;
    nm.x = fmaf(m.x, 1.0f - ww * e0, ww * ad0);
    nm.y = fmaf(m.y, 1.0f - ww * e1, ww * ad1);
    nm.z = fmaf(m.z, 1.0f - ww * e2, ww * ad2);
    nm.w = fmaf(m.w, 1.0f - ww * e3, ww * ad3);
    *(float4*)(nmem + base) = nm;
  }

  red0[tid] = acc0;
  red1[tid] = acc1;
  __syncthreads();
#pragma unroll
  for (int s = 128; s >= 32; s >>= 1) {
    if (tid < s) {
      float4 x = red0[tid], y = red0[tid + s];
      x.x += y.x; x.y += y.y; x.z += y.z; x.w += y.w;
      red0[tid] = x;
      float4 u = red1[tid], v = red1[tid + s];
      u.x += v.x; u.y += v.y; u.z += v.z; u.w += v.w;
      red1[tid] = u;
    }
    __syncthreads();
  }
  if (tid < 32) {
    float4 r0 = red0[tid];
    float4 r1 = red1[tid];
    float* rv0 = rv + (size_t)(0 * B_ + b) * C_ + (tid << 2);
    float* rv1 = rv + (size_t)(1 * B_ + b) * C_ + (tid << 2);
    atomicAdd(rv0 + 0, r0.x);
    atomicAdd(rv0 + 1, r0.y);
    atomicAdd(rv0 + 2, r0.z);
    atomicAdd(rv0 + 3, r0.w);
    atomicAdd(rv1 + 0, r1.x);
    atomicAdd(rv1 + 1, r1.y);
    atomicAdd(rv1 + 2, r1.z);
    atomicAdd(rv1 + 3, r1.w);
  }
}

extern "C" void kernel_launch(void* const* d_in, const int* in_sizes, int n_in,
                              void* d_out, int out_size, void* d_ws, size_t ws_size,
                              hipStream_t stream) {
  const float* h   = (const float*)d_in[0];
  const float* mem = (const float*)d_in[1];
  const float* ra  = (const float*)d_in[2];
  const float* wa  = (const float*)d_in[3];
  const float* Wr  = (const float*)d_in[4];
  const float* br  = (const float*)d_in[5];
  const float* Ww  = (const float*)d_in[6];
  const float* bw  = (const float*)d_in[7];

  float* out = (float*)d_out;
  float* rv = out;                               // [NR][B][C]
  float* nmem = out + NR_ * B_ * C_;             // [B][A][C]

  float* ws = (float*)d_ws;
  float* pr_buf = ws;                            // NR*B*PR   = 34304
  float* pw_buf = pr_buf + NR_ * B_ * PR_;       // B*PW      = 49920
  float* qbuf   = pw_buf + B_ * PW_;             // 3*B*C     = 49152
  float* qn     = qbuf + 3 * B_ * C_;            // 3*B       = 384
  float* pars   = qn + 3 * B_;                   // 3*B*8     = 3072
  float* simb   = pars + 3 * B_ * 8;             // 3*B*A     = 786432 (sim, attn in-place)

  constexpr int NWAVES = NR_ * B_ * PR_ + B_ * PW_;  // 84224
  proj_kernel<<<dim3((NWAVES + 3) / 4), dim3(256), 0, stream>>>(h, Wr, br, Ww, bw, pr_buf, pw_buf);
  headprep_kernel<<<dim3(3 * B_), dim3(64), 0, stream>>>(pr_buf, pw_buf, qbuf, qn, pars);
  sim_kernel<<<dim3(B_ * (A_ / 64)), dim3(256), 0, stream>>>(mem, qbuf, qn, simb);
  zero_rv_kernel<<<dim3((NR_ * B_ * C_ + 255) / 256), dim3(256), 0, stream>>>(rv);
  attn_kernel<<<dim3(3 * B_), dim3(256), 0, stream>>>(simb, ra, wa, pars, simb);
  update_kernel<<<dim3(B_ * (A_ / 256)), dim3(256), 0, stream>>>(mem, simb, pw_buf, rv, nmem);
}

// Round 3
// 291.791 us; speedup vs baseline: 1.0447x; 1.0447x over previous
//
#include <hip/hip_runtime.h>
#include <math.h>

constexpr int B_  = 128;
constexpr int A_  = 2048;
constexpr int C_  = 128;
constexpr int H_  = 512;
constexpr int S_  = 3;
constexpr int NR_ = 2;
constexpr int PR_ = C_ + 3 + S_;      // 134
constexpr int PW_ = 3 * C_ + 3 + S_;  // 390

typedef float vfloat4 __attribute__((ext_vector_type(4)));

__device__ __forceinline__ float sigmoidf_(float x) { return 1.0f / (1.0f + expf(-x)); }
__device__ __forceinline__ float softplusf_(float x) {
  return fmaxf(x, 0.0f) + log1pf(expf(-fabsf(x)));
}

__device__ __forceinline__ float waveReduceSum(float v) {
#pragma unroll
  for (int off = 32; off; off >>= 1) v += __shfl_xor(v, off, 64);
  return v;
}
__device__ __forceinline__ float waveReduceMax(float v) {
#pragma unroll
  for (int off = 32; off; off >>= 1) v = fmaxf(v, __shfl_xor(v, off, 64));
  return v;
}

// blockDim == 256 (4 waves)
__device__ __forceinline__ float blockReduceSum(float v, float* rbuf) {
  int tid = threadIdx.x;
  v = waveReduceSum(v);
  if ((tid & 63) == 0) rbuf[tid >> 6] = v;
  __syncthreads();
  float r = rbuf[0] + rbuf[1] + rbuf[2] + rbuf[3];
  __syncthreads();
  return r;
}
__device__ __forceinline__ float blockReduceMax(float v, float* rbuf) {
  int tid = threadIdx.x;
  v = waveReduceMax(v);
  if ((tid & 63) == 0) rbuf[tid >> 6] = v;
  __syncthreads();
  float r = fmaxf(fmaxf(rbuf[0], rbuf[1]), fmaxf(rbuf[2], rbuf[3]));
  __syncthreads();
  return r;
}

// ---------------------------------------------------------------------------
// Kernel 1: projections. One wave per output scalar (K=512 dot).
// ---------------------------------------------------------------------------
__global__ __launch_bounds__(256) void proj_kernel(
    const float* __restrict__ h, const float* __restrict__ Wr,
    const float* __restrict__ br, const float* __restrict__ Ww,
    const float* __restrict__ bw, float* __restrict__ pr, float* __restrict__ pw) {
  constexpr int NPR = NR_ * B_ * PR_;   // 34304
  constexpr int NPW = B_ * PW_;         // 49920
  int wave = (blockIdx.x * blockDim.x + threadIdx.x) >> 6;
  int lane = threadIdx.x & 63;
  const float* wrow;
  const float* hrow;
  float bias;
  float* outp;
  if (wave < NPR) {
    int r = wave / (B_ * PR_);
    int rem = wave - r * (B_ * PR_);
    int b = rem / PR_;
    int p = rem - b * PR_;
    wrow = Wr + (size_t)(r * PR_ + p) * H_;
    hrow = h + (size_t)b * H_;
    bias = br[r * PR_ + p];
    outp = pr + wave;
  } else {
    int w2 = wave - NPR;
    if (w2 >= NPW) return;
    int b = w2 / PW_;
    int p = w2 - b * PW_;
    wrow = Ww + (size_t)p * H_;
    hrow = h + (size_t)b * H_;
    bias = bw[p];
    outp = pw + w2;
  }
  const float4* w4 = (const float4*)wrow;
  const float4* h4 = (const float4*)hrow;
  float4 a0 = h4[(lane << 1)];
  float4 a1 = h4[(lane << 1) + 1];
  float4 b0 = w4[(lane << 1)];
  float4 b1 = w4[(lane << 1) + 1];
  float acc = a0.x * b0.x;
  acc = fmaf(a0.y, b0.y, acc);
  acc = fmaf(a0.z, b0.z, acc);
  acc = fmaf(a0.w, b0.w, acc);
  acc = fmaf(a1.x, b1.x, acc);
  acc = fmaf(a1.y, b1.y, acc);
  acc = fmaf(a1.z, b1.z, acc);
  acc = fmaf(a1.w, b1.w, acc);
  acc = waveReduceSum(acc);
  if (lane == 0) *outp = acc + bias;
}

// ---------------------------------------------------------------------------
// Kernel 2: headprep (q sigmoid + norms + scalar params) fused with zeroing
// the read_vectors accumulator region. grid = 3*B = 384, block = 64.
// ---------------------------------------------------------------------------
__global__ __launch_bounds__(64) void headprep_kernel(
    const float* __restrict__ pr, const float* __restrict__ pw,
    float* __restrict__ qbuf, float* __restrict__ qn, float* __restrict__ pars,
    float* __restrict__ rv) {
  int hb = blockIdx.x;          // hd*B + b
  int hd = hb >> 7;
  int b = hb & (B_ - 1);
  int lane = threadIdx.x;
  // fused: zero rv [NR*B*C = 32768 floats] across 384*64 = 24576 threads
  for (int i = hb * 64 + lane; i < NR_ * B_ * C_; i += 384 * 64) rv[i] = 0.0f;

  const float* src = (hd < 2) ? (pr + (size_t)hb * PR_) : (pw + (size_t)b * PW_);
  float2 raw = ((const float2*)src)[lane];   // c = lane*2, lane*2+1
  float q0 = sigmoidf_(raw.x);
  float q1 = sigmoidf_(raw.y);
  ((float2*)(qbuf + (size_t)hb * C_))[lane] = make_float2(q0, q1);
  float ss = q0 * q0 + q1 * q1;
  ss = waveReduceSum(ss);
  if (lane == 0) {
    qn[hb] = fmaxf(sqrtf(ss), 1e-8f);
    float braw = src[C_];
    float graw = src[C_ + 1];
    float s0 = src[C_ + 2], s1 = src[C_ + 3], s2 = src[C_ + 4];
    float gmraw = src[C_ + 5];
    float mx = fmaxf(s0, fmaxf(s1, s2));
    float e0 = expf(s0 - mx), e1 = expf(s1 - mx), e2 = expf(s2 - mx);
    float inv = 1.0f / (e0 + e1 + e2);
    float* pp = pars + hb * 8;
    pp[0] = softplusf_(braw) + 1.0f;   // beta
    pp[1] = sigmoidf_(graw);           // gate
    pp[2] = e0 * inv;                  // shift_w[0]
    pp[3] = e1 * inv;
    pp[4] = e2 * inv;
    pp[5] = softplusf_(gmraw) + 1.0f;  // gamma
  }
}

// ---------------------------------------------------------------------------
// Kernel 3: sim pass over mem. 8 lanes per row; q fragments in registers;
// reduce = 3 shfl levels (xor 1,2,4). grid = B * A/64 = 4096, block 256.
// ---------------------------------------------------------------------------
__global__ __launch_bounds__(256) void sim_kernel(
    const float* __restrict__ mem, const float* __restrict__ qbuf,
    const float* __restrict__ qn, float* __restrict__ sim) {
  __shared__ __align__(16) float qs[3 * C_];
  __shared__ float qnl[3];
  int b = blockIdx.x >> 5;
  int chunk = blockIdx.x & 31;
  int rowbase = chunk << 6;
  int tid = threadIdx.x;
  for (int idx = tid; idx < 3 * C_; idx += 256) {
    int hd = idx >> 7;
    int c = idx & (C_ - 1);
    qs[idx] = qbuf[(size_t)(hd * B_ + b) * C_ + c];
  }
  if (tid < 3) qnl[tid] = qn[tid * B_ + b];
  __syncthreads();

  int wv = tid >> 6;
  int lane = tid & 63;
  int j = lane & 7;       // quad subgroup within row
  int rsub = lane >> 3;   // row within wave-iter (0..7)

  float4 q0[4], q1[4], q2[4];
  const float4* qs4 = (const float4*)qs;
#pragma unroll
  for (int k = 0; k < 4; k++) {
    q0[k] = qs4[j + 8 * k];
    q1[k] = qs4[32 + j + 8 * k];
    q2[k] = qs4[64 + j + 8 * k];
  }
  float iqn0 = 1.0f / qnl[0], iqn1 = 1.0f / qnl[1], iqn2 = 1.0f / qnl[2];

#pragma unroll
  for (int it = 0; it < 2; it++) {
    int row = rowbase + (it << 5) + (wv << 3) + rsub;
    const float4* mrow = (const float4*)(mem + ((size_t)b * A_ + row) * C_);
    float d0 = 0.f, d1 = 0.f, d2 = 0.f, ss = 0.f;
#pragma unroll
    for (int k = 0; k < 4; k++) {
      float4 m = mrow[j + 8 * k];
      d0 = fmaf(m.x, q0[k].x, d0); d0 = fmaf(m.y, q0[k].y, d0);
      d0 = fmaf(m.z, q0[k].z, d0); d0 = fmaf(m.w, q0[k].w, d0);
      d1 = fmaf(m.x, q1[k].x, d1); d1 = fmaf(m.y, q1[k].y, d1);
      d1 = fmaf(m.z, q1[k].z, d1); d1 = fmaf(m.w, q1[k].w, d1);
      d2 = fmaf(m.x, q2[k].x, d2); d2 = fmaf(m.y, q2[k].y, d2);
      d2 = fmaf(m.z, q2[k].z, d2); d2 = fmaf(m.w, q2[k].w, d2);
      ss = fmaf(m.x, m.x, ss); ss = fmaf(m.y, m.y, ss);
      ss = fmaf(m.z, m.z, ss); ss = fmaf(m.w, m.w, ss);
    }
#pragma unroll
    for (int off = 1; off <= 4; off <<= 1) {
      d0 += __shfl_xor(d0, off, 64);
      d1 += __shfl_xor(d1, off, 64);
      d2 += __shfl_xor(d2, off, 64);
      ss += __shfl_xor(ss, off, 64);
    }
    if (j == 0) {
      float imn = 1.0f / fmaxf(sqrtf(ss), 1e-8f);
      sim[(size_t)(0 * B_ + b) * A_ + row] = d0 * iqn0 * imn;
      sim[(size_t)(1 * B_ + b) * A_ + row] = d1 * iqn1 * imn;
      sim[(size_t)(2 * B_ + b) * A_ + row] = d2 * iqn2 * imn;
    }
  }
}

// ---------------------------------------------------------------------------
// Kernel 4: attention per (head,b). Writes IN-PLACE over sim.
// ---------------------------------------------------------------------------
__global__ __launch_bounds__(256) void attn_kernel(
    const float* __restrict__ sim, const float* __restrict__ ra,
    const float* __restrict__ wa, const float* __restrict__ pars,
    float* __restrict__ attn) {
  __shared__ float wg[A_];
  __shared__ float rbuf[4];
  int hb = blockIdx.x;
  int hd = hb >> 7;
  int b = hb & (B_ - 1);
  int tid = threadIdx.x;
  const float* pp = pars + hb * 8;
  float beta = pp[0], gate = pp[1], sw0 = pp[2], sw1 = pp[3], sw2 = pp[4], gamma = pp[5];
  const float* simrow = sim + (size_t)hb * A_;
  const float* prev = (hd < 2) ? (ra + (size_t)hb * A_) : (wa + (size_t)b * A_);
  float* outrow = attn + (size_t)hb * A_;

  float s[8];
  float mx = -1e30f;
#pragma unroll
  for (int i = 0; i < 8; i++) {
    s[i] = simrow[tid + (i << 8)];
    mx = fmaxf(mx, s[i]);
  }
  mx = blockReduceMax(mx, rbuf);
  float p[8];
  float lsum = 0.0f;
#pragma unroll
  for (int i = 0; i < 8; i++) {
    p[i] = expf(beta * (s[i] - mx));
    lsum += p[i];
  }
  float tot = blockReduceSum(lsum, rbuf);
  float inv = 1.0f / tot;
#pragma unroll
  for (int i = 0; i < 8; i++) {
    int a = tid + (i << 8);
    wg[a] = fmaf(gate, p[i] * inv, (1.0f - gate) * prev[a]);
  }
  __syncthreads();
  float lsum2 = 0.0f;
#pragma unroll
  for (int i = 0; i < 8; i++) {
    int a = tid + (i << 8);
    float ws = sw0 * wg[(a + 1) & (A_ - 1)] + sw1 * wg[a] + sw2 * wg[(a - 1) & (A_ - 1)];
    float wp = (ws > 0.0f) ? exp2f(gamma * log2f(ws)) : 0.0f;
    p[i] = wp;
    lsum2 += wp;
  }
  float tot2 = blockReduceSum(lsum2, rbuf);
  float inv2 = 1.0f / (tot2 + 1e-12f);
#pragma unroll
  for (int i = 0; i < 8; i++) {
    outrow[tid + (i << 8)] = p[i] * inv2;
  }
}

// ---------------------------------------------------------------------------
// Kernel 5: second pass over mem. read_vectors + new_mem. Nontemporal stores
// for new_mem keep `mem` L3-resident for this kernel's own reads.
// ---------------------------------------------------------------------------
__global__ __launch_bounds__(256) void update_kernel(
    const float* __restrict__ mem, const float* __restrict__ attn,
    const float* __restrict__ pw, float* __restrict__ rv,
    float* __restrict__ nmem) {
  __shared__ float att0[256], att1[256], attw[256];
  __shared__ float4 red0[256];
  __shared__ float4 red1[256];
  int b = blockIdx.x >> 3;
  int chunk = blockIdx.x & 7;
  int rowbase = chunk << 8;
  int tid = threadIdx.x;
  att0[tid] = attn[(size_t)(0 * B_ + b) * A_ + rowbase + tid];
  att1[tid] = attn[(size_t)(1 * B_ + b) * A_ + rowbase + tid];
  attw[tid] = attn[(size_t)(2 * B_ + b) * A_ + rowbase + tid];
  __syncthreads();

  int rowlane = tid & 31;
  int rowoff = tid >> 5;
  int c0 = rowlane << 2;
  const float* pwrow = pw + (size_t)b * PW_;
  float2 eA = *(const float2*)(pwrow + C_ + 6 + c0);        // erase at offset 134
  float2 eB = *(const float2*)(pwrow + C_ + 6 + c0 + 2);
  float2 aA = *(const float2*)(pwrow + 2 * C_ + 6 + c0);    // add at offset 262
  float2 aB = *(const float2*)(pwrow + 2 * C_ + 6 + c0 + 2);
  float e0 = sigmoidf_(eA.x), e1 = sigmoidf_(eA.y), e2 = sigmoidf_(eB.x), e3 = sigmoidf_(eB.y);
  float ad0 = sigmoidf_(aA.x), ad1 = sigmoidf_(aA.y), ad2 = sigmoidf_(aB.x), ad3 = sigmoidf_(aB.y);

  float4 acc0 = make_float4(0.f, 0.f, 0.f, 0.f);
  float4 acc1 = make_float4(0.f, 0.f, 0.f, 0.f);

#pragma unroll 4
  for (int i = 0; i < 32; i++) {
    int ridx = (i << 3) + rowoff;
    int row = rowbase + ridx;
    size_t base = ((size_t)b * A_ + row) * C_ + c0;
    float4 m = *(const float4*)(mem + base);
    float w0 = att0[ridx];
    float w1 = att1[ridx];
    float ww = attw[ridx];
    acc0.x = fmaf(w0, m.x, acc0.x);
    acc0.y = fmaf(w0, m.y, acc0.y);
    acc0.z = fmaf(w0, m.z, acc0.z);
    acc0.w = fmaf(w0, m.w, acc0.w);
    acc1.x = fmaf(w1, m.x, acc1.x);
    acc1.y = fmaf(w1, m.y, acc1.y);
    acc1.z = fmaf(w1, m.z, acc1.z);
    acc1.w = fmaf(w1, m.w, acc1.w);
    vfloat4 nm;
    nm.x = fmaf(m.x, 1.0f - ww * e0, ww * ad0);
    nm.y = fmaf(m.y, 1.0f - ww * e1, ww * ad1);
    nm.z = fmaf(m.z, 1.0f - ww * e2, ww * ad2);
    nm.w = fmaf(m.w, 1.0f - ww * e3, ww * ad3);
    __builtin_nontemporal_store(nm, (vfloat4*)(nmem + base));
  }

  red0[tid] = acc0;
  red1[tid] = acc1;
  __syncthreads();
#pragma unroll
  for (int s = 128; s >= 32; s >>= 1) {
    if (tid < s) {
      float4 x = red0[tid], y = red0[tid + s];
      x.x += y.x; x.y += y.y; x.z += y.z; x.w += y.w;
      red0[tid] = x;
      float4 u = red1[tid], v = red1[tid + s];
      u.x += v.x; u.y += v.y; u.z += v.z; u.w += v.w;
      red1[tid] = u;
    }
    __syncthreads();
  }
  if (tid < 32) {
    float4 r0 = red0[tid];
    float4 r1 = red1[tid];
    float* rv0 = rv + (size_t)(0 * B_ + b) * C_ + (tid << 2);
    float* rv1 = rv + (size_t)(1 * B_ + b) * C_ + (tid << 2);
    atomicAdd(rv0 + 0, r0.x);
    atomicAdd(rv0 + 1, r0.y);
    atomicAdd(rv0 + 2, r0.z);
    atomicAdd(rv0 + 3, r0.w);
    atomicAdd(rv1 + 0, r1.x);
    atomicAdd(rv1 + 1, r1.y);
    atomicAdd(rv1 + 2, r1.z);
    atomicAdd(rv1 + 3, r1.w);
  }
}

extern "C" void kernel_launch(void* const* d_in, const int* in_sizes, int n_in,
                              void* d_out, int out_size, void* d_ws, size_t ws_size,
                              hipStream_t stream) {
  const float* h   = (const float*)d_in[0];
  const float* mem = (const float*)d_in[1];
  const float* ra  = (const float*)d_in[2];
  const float* wa  = (const float*)d_in[3];
  const float* Wr  = (const float*)d_in[4];
  const float* br  = (const float*)d_in[5];
  const float* Ww  = (const float*)d_in[6];
  const float* bw  = (const float*)d_in[7];

  float* out = (float*)d_out;
  float* rv = out;                               // [NR][B][C]
  float* nmem = out + NR_ * B_ * C_;             // [B][A][C]

  float* ws = (float*)d_ws;
  float* pr_buf = ws;                            // NR*B*PR   = 34304
  float* pw_buf = pr_buf + NR_ * B_ * PR_;       // B*PW      = 49920
  float* qbuf   = pw_buf + B_ * PW_;             // 3*B*C     = 49152
  float* qn     = qbuf + 3 * B_ * C_;            // 3*B       = 384
  float* pars   = qn + 3 * B_;                   // 3*B*8     = 3072
  float* simb   = pars + 3 * B_ * 8;             // 3*B*A     = 786432 (sim, attn in-place)

  constexpr int NWAVES = NR_ * B_ * PR_ + B_ * PW_;  // 84224
  proj_kernel<<<dim3((NWAVES + 3) / 4), dim3(256), 0, stream>>>(h, Wr, br, Ww, bw, pr_buf, pw_buf);
  headprep_kernel<<<dim3(3 * B_), dim3(64), 0, stream>>>(pr_buf, pw_buf, qbuf, qn, pars, rv);
  sim_kernel<<<dim3(B_ * (A_ / 64)), dim3(256), 0, stream>>>(mem, qbuf, qn, simb);
  attn_kernel<<<dim3(3 * B_), dim3(256), 0, stream>>>(simb, ra, wa, pars, simb);
  update_kernel<<<dim3(B_ * (A_ / 256)), dim3(256), 0, stream>>>(mem, simb, pw_buf, rv, nmem);
}